// Round 5
// baseline (406.058 us; speedup 1.0000x reference)
//
#include <hip/hip_runtime.h>
#include <hip/hip_bf16.h>

typedef __bf16 bf16;
typedef __attribute__((ext_vector_type(2))) __bf16 bf16x2;
typedef __attribute__((ext_vector_type(4))) __bf16 bf16x4;
typedef __attribute__((ext_vector_type(8))) __bf16 bf16x8;
typedef __attribute__((ext_vector_type(4))) float f32x4;

#define NB 2
#define SEQ 1024
#define HIDN 4096
#define NH 32
#define NKV 8
#define DH 128
#define QKV_N 6144
static constexpr float SCALE = 0.08838834764831845f;  // 1/sqrt(128)

#define MFMA(a, b, c) __builtin_amdgcn_mfma_f32_16x16x32_bf16((a), (b), (c), 0, 0, 0)

__device__ __forceinline__ void async16(const void* g, void* l) {
  __builtin_amdgcn_global_load_lds(
      (const __attribute__((address_space(1))) unsigned int*)g,
      (__attribute__((address_space(3))) unsigned int*)l,
      16, 0, 0);
}

__device__ __forceinline__ void barrier_raw() {
  asm volatile("" ::: "memory");
  __builtin_amdgcn_s_barrier();
  asm volatile("" ::: "memory");
}
#define VMCNT(n) asm volatile("s_waitcnt vmcnt(" #n ")" ::: "memory")

// ---------------- f32 -> bf16 convert (vector) ----------------
__global__ __launch_bounds__(256) void cvt_f32_bf16(const float* __restrict__ src,
                                                    bf16* __restrict__ dst, int n4) {
  int i = blockIdx.x * 256 + threadIdx.x;
  if (i >= n4) return;
  const float4 v = ((const float4*)src)[i];
  bf16x4 o = {(bf16)v.x, (bf16)v.y, (bf16)v.z, (bf16)v.w};
  ((bf16x4*)dst)[i] = o;
}

// ---------------- transpose + convert: dst[N][K] = (bf16)src[K][N] ----------------
__global__ __launch_bounds__(256) void transpose_cvt(const float* __restrict__ src,
                                                     bf16* __restrict__ dst, int R, int C) {
  __shared__ float tl[32][33];
  const int j0 = blockIdx.x * 32, i0 = blockIdx.y * 32;
  const int tr = threadIdx.x >> 5, tc = threadIdx.x & 31;
#pragma unroll
  for (int p = 0; p < 4; ++p)
    tl[tr + p * 8][tc] = src[(size_t)(i0 + tr + p * 8) * C + j0 + tc];
  __syncthreads();
#pragma unroll
  for (int p = 0; p < 4; ++p)
    dst[(size_t)(j0 + tr + p * 8) * R + i0 + tc] = (bf16)tl[tc][tr + p * 8];
}

// ---------------- 8-phase deep-pipelined bf16 GEMM (m201-style, T2+T3+T4+T5+T1) ----
// C[M][N] = A[M][K] * BT[N][K]^T.  BM=256, BK=64, 512 thr = 8 waves (2M x 4N).
// LDS: 2 K-tile buffers, each [A-K0 | B-K0 | A-K1 | B-K1] chunks of 64B rows,
// slot swizzle slot16 ^= (row>>1)&3 (0-conflict, verified R3/R4).
// Per phase: 10 ds_read_b128 -> 1 stage unit of tile t+1 -> barrier ->
// setprio+16 MFMA -> counted VMCNT (never 0 mid-loop) -> barrier.
#define GPHASE(KH, CH, STAGE_STMT, VM_STMT)                              \
  {                                                                      \
    const char* kb = bc + (KH) * (CA + CB);                              \
    bf16x8 b0 = *(const bf16x8*)(kb + CA + bbyte[(CH)*2 + 0]);           \
    bf16x8 b1 = *(const bf16x8*)(kb + CA + bbyte[(CH)*2 + 1]);           \
    bf16x8 af[8];                                                        \
    _Pragma("unroll") for (int fm = 0; fm < 8; ++fm)                     \
        af[fm] = *(const bf16x8*)(kb + abyte[fm]);                       \
    STAGE_STMT;                                                          \
    barrier_raw();                                                       \
    __builtin_amdgcn_s_setprio(1);                                       \
    _Pragma("unroll") for (int fm = 0; fm < 8; ++fm) {                   \
      acc[fm][(CH)*2 + 0] = MFMA(af[fm], b0, acc[fm][(CH)*2 + 0]);       \
      acc[fm][(CH)*2 + 1] = MFMA(af[fm], b1, acc[fm][(CH)*2 + 1]);       \
    }                                                                    \
    __builtin_amdgcn_s_setprio(0);                                       \
    VM_STMT;                                                             \
    barrier_raw();                                                       \
  }

template <int BN, int OUT_BF16>
__global__ __launch_bounds__(512, 2) void gemm_8ph(const bf16* __restrict__ A,
                                                   const bf16* __restrict__ BT,
                                                   void* __restrict__ Cout,
                                                   int N, int K, int nbn) {
  extern __shared__ char smem[];
  constexpr int CA = 256 * 32 * 2;    // 16 KiB A k-half chunk
  constexpr int CB = BN * 32 * 2;     // 16 / 8 KiB B k-half chunk
  constexpr int BUF = 2 * (CA + CB);  // one K-tile buffer
  constexpr int FNT = BN / 64;        // 4 or 2 n-fragments per wave
  const int t = threadIdx.x, lane = t & 63, w = t >> 6;
  const int l16 = lane & 15, lq = lane >> 4;
  const int wm = w >> 2, wn = w & 3;

  const int nwg = gridDim.x;  // divisible by 8
  const int lin = ((int)blockIdx.x & 7) * (nwg >> 3) + ((int)blockIdx.x >> 3);
  const int m0 = (lin / nbn) * 256, n0 = (lin % nbn) * BN;

  // staging sources: pre-swizzled global col-slot, linear LDS dest
  const int srow = t >> 2;
  const int sslot = (t & 3) ^ ((srow >> 1) & 3);  // (row+128) gives same xor
  const bf16* gA0 = A + (size_t)(m0 + srow) * K + sslot * 8;
  const bf16* gA1 = A + (size_t)(m0 + srow + 128) * K + sslot * 8;
  const bf16* gB0 = BT + (size_t)(n0 + srow) * K + sslot * 8;
  const bf16* gB1 = BT + (size_t)(n0 + ((BN == 256) ? srow + 128 : srow)) * K + sslot * 8;

  // swizzled fragment byte offsets within a chunk
  int abyte[8], bbyte[FNT];
#pragma unroll
  for (int fm = 0; fm < 8; ++fm) {
    const int r = wm * 128 + fm * 16 + l16;
    abyte[fm] = r * 64 + ((lq ^ ((r >> 1) & 3)) << 4);
  }
#pragma unroll
  for (int j = 0; j < FNT; ++j) {
    const int r = wn * (BN / 4) + j * 16 + l16;
    bbyte[j] = r * 64 + ((lq ^ ((r >> 1) & 3)) << 4);
  }

  auto stageA = [&](int bsel, int kt, int kh) {
    char* dst = smem + bsel * BUF + kh * (CA + CB) + t * 16;
    const int ko = kt * 64 + kh * 32;
    async16(gA0 + ko, dst);
    async16(gA1 + ko, dst + 8192);
  };
  auto stageB = [&](int bsel, int kt, int kh) {
    char* dst = smem + bsel * BUF + kh * (CA + CB) + CA + t * 16;
    const int ko = kt * 64 + kh * 32;
    async16(gB0 + ko, dst);
    if constexpr (BN == 256) async16(gB1 + ko, dst + 8192);
  };

  f32x4 acc[8][FNT] = {};
  const int NT = K >> 6;

  // prologue: stage tile 0 fully, wait for its first half (A0,B0)
  stageA(0, 0, 0);
  stageB(0, 0, 0);
  stageA(0, 0, 1);
  stageB(0, 0, 1);
  if constexpr (BN == 256) { VMCNT(4); } else { VMCNT(3); }
  barrier_raw();

  for (int kt = 0; kt < NT; ++kt) {
    const char* bc = smem + (kt & 1) * BUF;
    const int nb = (kt + 1) & 1;
    const bool pf = (kt + 1 < NT);
    if constexpr (BN == 256) {
      GPHASE(0, 0, { if (pf) stageA(nb, kt + 1, 0); }, {});
      GPHASE(0, 1, { if (pf) stageB(nb, kt + 1, 0); },
             { if (pf) { VMCNT(4); } else { VMCNT(0); } });
      GPHASE(1, 0, { if (pf) stageA(nb, kt + 1, 1); }, {});
      GPHASE(1, 1, { if (pf) stageB(nb, kt + 1, 1); }, { if (pf) { VMCNT(4); } });
    } else {
      GPHASE(0, 0, { if (pf) { stageA(nb, kt + 1, 0); stageB(nb, kt + 1, 0); } },
             { if (pf) { VMCNT(3); } else { VMCNT(0); } });
      GPHASE(1, 0, { if (pf) { stageA(nb, kt + 1, 1); stageB(nb, kt + 1, 1); } },
             { if (pf) { VMCNT(3); } });
    }
  }

#pragma unroll
  for (int fm = 0; fm < 8; ++fm)
#pragma unroll
    for (int j = 0; j < FNT; ++j)
#pragma unroll
      for (int r = 0; r < 4; ++r) {
        const int row = m0 + wm * 128 + fm * 16 + lq * 4 + r;
        const int col = n0 + wn * (BN / 4) + j * 16 + l16;
        if (OUT_BF16)
          ((bf16*)Cout)[(size_t)row * N + col] = (bf16)acc[fm][j][r];
        else
          ((float*)Cout)[(size_t)row * N + col] = acc[fm][j][r];
      }
}

// ---------------- RoPE + reshape: qkv -> Q[b][h][s][d] (scaled), K[b][kv][s][d], VT[b][kv][d][s] ----------------
__global__ __launch_bounds__(256) void rope_reshape(const bf16* __restrict__ qkv,
                                                    const float* __restrict__ cosp,
                                                    const float* __restrict__ sinp,
                                                    bf16* __restrict__ Qo,
                                                    bf16* __restrict__ Ko,
                                                    bf16* __restrict__ VTo) {
  const int row = blockIdx.x;          // b*SEQ + s
  const int b = row >> 10, s = row & 1023;
  const bf16* src = qkv + (size_t)row * QKV_N;
  for (int p = threadIdx.x; p < QKV_N / 2; p += 256) {
    const int col = p * 2;
    bf16x2 x = *(const bf16x2*)&src[col];
    const float x1 = (float)x.x, x2 = (float)x.y;
    if (col < 4096) {
      const int h = col >> 7, d = col & 127, i = (col & 127) >> 1;
      const float c = cosp[s * 64 + i], sn = sinp[s * 64 + i];
      bf16x2 o = {(bf16)((x1 * c - x2 * sn) * SCALE), (bf16)((x1 * sn + x2 * c) * SCALE)};
      *(bf16x2*)&Qo[((size_t)(b * NH + h) * SEQ + s) * DH + d] = o;
    } else if (col < 5120) {
      const int idx = col - 4096;
      const int kvh = idx >> 7, d = idx & 127, i = (idx & 127) >> 1;
      const float c = cosp[s * 64 + i], sn = sinp[s * 64 + i];
      bf16x2 o = {(bf16)(x1 * c - x2 * sn), (bf16)(x1 * sn + x2 * c)};
      *(bf16x2*)&Ko[((size_t)(b * NKV + kvh) * SEQ + s) * DH + d] = o;
    } else {
      const int idx = col - 5120;
      const int kvh = idx >> 7, d = idx & 127;
      bf16* vbase = VTo + ((size_t)(b * NKV + kvh) * DH + d) * SEQ + s;
      vbase[0] = x.x;
      vbase[SEQ] = x.y;
    }
  }
}

// ---------------- causal GQA flash attention, paired q-tiles ----------------
__global__ __launch_bounds__(256, 2) void flash_attn(const bf16* __restrict__ Q,
                                                     const bf16* __restrict__ K,
                                                     const bf16* __restrict__ VT,
                                                     bf16* __restrict__ O) {
  const int lane = threadIdx.x & 63, w = threadIdx.x >> 6;
  const int l16 = lane & 15, lq = lane >> 4;
  const int p = blockIdx.x * 4 + w;  // 0..2047
  const int b = p >> 10, h = (p >> 5) & 31, t = p & 31;
  const int kvh = h >> 2;  // G = 4

  const bf16* Qb = Q + (size_t)(b * NH + h) * SEQ * DH;
  const bf16* Kb = K + (size_t)(b * NKV + kvh) * SEQ * DH;
  const bf16* Vb = VT + (size_t)(b * NKV + kvh) * DH * SEQ;

  const int qrA = t * 16, qrB = (63 - t) * 16;
  const int nA = t / 4 + 1, nB = (63 - t) / 4 + 1;

  __shared__ bf16 plds[4][2][16][72];

  bf16x8 qfA[4], qfB[4];
#pragma unroll
  for (int kk = 0; kk < 4; ++kk) {
    qfA[kk] = *(const bf16x8*)&Qb[(size_t)(qrA + l16) * DH + kk * 32 + lq * 8];
    qfB[kk] = *(const bf16x8*)&Qb[(size_t)(qrB + l16) * DH + kk * 32 + lq * 8];
  }

  f32x4 accA[8] = {}, accB[8] = {};
  float mA[4], lA[4], mB[4], lB[4];
#pragma unroll
  for (int r = 0; r < 4; ++r) {
    mA[r] = mB[r] = -INFINITY;
    lA[r] = lB[r] = 0.f;
  }

  auto finish = [&](f32x4(&s)[4], float(&m)[4], float(&l)[4], f32x4(&acc)[8], int slot,
                    bool mask, int kv, int qr) {
    if (mask) {
#pragma unroll
      for (int nt = 0; nt < 4; ++nt)
#pragma unroll
        for (int r = 0; r < 4; ++r)
          if (kv * 64 + nt * 16 + l16 > qr + lq * 4 + r) s[nt][r] = -INFINITY;
    }
#pragma unroll
    for (int r = 0; r < 4; ++r) {
      float mx = fmaxf(fmaxf(s[0][r], s[1][r]), fmaxf(s[2][r], s[3][r]));
#pragma unroll
      for (int off = 1; off < 16; off <<= 1) mx = fmaxf(mx, __shfl_xor(mx, off));
      const float mn = fmaxf(m[r], mx);
      const float corr = __expf(m[r] - mn);
      m[r] = mn;
      float ps = 0.f;
#pragma unroll
      for (int nt = 0; nt < 4; ++nt) {
        const float pv = __expf(s[nt][r] - mn);
        s[nt][r] = pv;
        ps += pv;
      }
#pragma unroll
      for (int off = 1; off < 16; off <<= 1) ps += __shfl_xor(ps, off);
      l[r] = l[r] * corr + ps;
#pragma unroll
      for (int j = 0; j < 8; ++j) acc[j][r] *= corr;
    }
#pragma unroll
    for (int nt = 0; nt < 4; ++nt)
#pragma unroll
      for (int r = 0; r < 4; ++r)
        plds[w][slot][lq * 4 + r][nt * 16 + l16] = (bf16)s[nt][r];
  };

  int kv = 0;
  for (; kv < nA; ++kv) {
    f32x4 sA[4] = {}, sB[4] = {};
    const bf16* kbase = &Kb[(size_t)(kv * 64 + l16) * DH + lq * 8];
#pragma unroll
    for (int nt = 0; nt < 4; ++nt) {
      const bf16* kr = kbase + (size_t)nt * 16 * DH;
      bf16x8 k0 = *(const bf16x8*)kr;
      bf16x8 k1 = *(const bf16x8*)(kr + 32);
      bf16x8 k2 = *(const bf16x8*)(kr + 64);
      bf16x8 k3 = *(const bf16x8*)(kr + 96);
      sA[nt] = MFMA(qfA[0], k0, sA[nt]);
      sB[nt] = MFMA(qfB[0], k0, sB[nt]);
      sA[nt] = MFMA(qfA[1], k1, sA[nt]);
      sB[nt] = MFMA(qfB[1], k1, sB[nt]);
      sA[nt] = MFMA(qfA[2], k2, sA[nt]);
      sB[nt] = MFMA(qfB[2], k2, sB[nt]);
      sA[nt] = MFMA(qfA[3], k3, sA[nt]);
      sB[nt] = MFMA(qfB[3], k3, sB[nt]);
    }
    finish(sA, mA, lA, accA, 0, kv == nA - 1, kv, qrA);
    finish(sB, mB, lB, accB, 1, false, kv, qrB);
    bf16x8 pA0 = *(const bf16x8*)&plds[w][0][l16][lq * 8];
    bf16x8 pA1 = *(const bf16x8*)&plds[w][0][l16][32 + lq * 8];
    bf16x8 pB0 = *(const bf16x8*)&plds[w][1][l16][lq * 8];
    bf16x8 pB1 = *(const bf16x8*)&plds[w][1][l16][32 + lq * 8];
    const bf16* vbase = &Vb[(size_t)l16 * SEQ + kv * 64 + lq * 8];
#pragma unroll
    for (int j = 0; j < 8; ++j) {
      const bf16* vr = vbase + (size_t)j * 16 * SEQ;
      bf16x8 v0 = *(const bf16x8*)vr;
      bf16x8 v1 = *(const bf16x8*)(vr + 32);
      accA[j] = MFMA(pA0, v0, accA[j]);
      accB[j] = MFMA(pB0, v0, accB[j]);
      accA[j] = MFMA(pA1, v1, accA[j]);
      accB[j] = MFMA(pB1, v1, accB[j]);
    }
  }
  for (; kv < nB; ++kv) {
    f32x4 sB[4] = {};
    const bf16* kbase = &Kb[(size_t)(kv * 64 + l16) * DH + lq * 8];
#pragma unroll
    for (int nt = 0; nt < 4; ++nt) {
      const bf16* kr = kbase + (size_t)nt * 16 * DH;
      bf16x8 k0 = *(const bf16x8*)kr;
      bf16x8 k1 = *(const bf16x8*)(kr + 32);
      bf16x8 k2 = *(const bf16x8*)(kr + 64);
      bf16x8 k3 = *(const bf16x8*)(kr + 96);
      sB[nt] = MFMA(qfB[0], k0, sB[nt]);
      sB[nt] = MFMA(qfB[1], k1, sB[nt]);
      sB[nt] = MFMA(qfB[2], k2, sB[nt]);
      sB[nt] = MFMA(qfB[3], k3, sB[nt]);
    }
    finish(sB, mB, lB, accB, 1, kv == nB - 1, kv, qrB);
    bf16x8 pB0 = *(const bf16x8*)&plds[w][1][l16][lq * 8];
    bf16x8 pB1 = *(const bf16x8*)&plds[w][1][l16][32 + lq * 8];
    const bf16* vbase = &Vb[(size_t)l16 * SEQ + kv * 64 + lq * 8];
#pragma unroll
    for (int j = 0; j < 8; ++j) {
      const bf16* vr = vbase + (size_t)j * 16 * SEQ;
      bf16x8 v0 = *(const bf16x8*)vr;
      bf16x8 v1 = *(const bf16x8*)(vr + 32);
      accB[j] = MFMA(pB0, v0, accB[j]);
      accB[j] = MFMA(pB1, v1, accB[j]);
    }
  }

  auto wout = [&](f32x4(&acc)[8], float(&l)[4], int qr) {
#pragma unroll
    for (int r = 0; r < 4; ++r) {
      const float inv = 1.f / l[r];
      const size_t orow = ((size_t)b * SEQ + qr + lq * 4 + r) * HIDN + h * DH;
#pragma unroll
      for (int j = 0; j < 8; ++j) O[orow + j * 16 + l16] = (bf16)(acc[j][r] * inv);
    }
  };
  wout(accA, lA, qrA);
  wout(accB, lB, qrB);
}

extern "C" void kernel_launch(void* const* d_in, const int* in_sizes, int n_in,
                              void* d_out, int out_size, void* d_ws, size_t ws_size,
                              hipStream_t stream) {
  const float* hidden = (const float*)d_in[0];
  const float* cosp = (const float*)d_in[1];
  const float* sinp = (const float*)d_in[2];
  const float* wqkv = (const float*)d_in[3];
  const float* wo = (const float*)d_in[4];
  float* out = (float*)d_out;

  char* ws = (char*)d_ws;
  bf16* hiddenB = (bf16*)(ws);                 // 16,777,216   [2048][4096]
  bf16* wqkvT  = (bf16*)(ws + 16777216);       // 50,331,648   [6144][4096]
  bf16* woT    = (bf16*)(ws + 67108864);       // 33,554,432   [4096][4096]
  bf16* qkvB   = (bf16*)(ws + 100663296);      // 25,165,824   [2048][6144]
  bf16* Qb     = (bf16*)(ws + 125829120);      // 16,777,216   [2][32][1024][128]
  bf16* Kb     = (bf16*)(ws + 142606336);      //  4,194,304   [2][8][1024][128]
  bf16* VTb    = (bf16*)(ws + 146800640);      //  4,194,304   [2][8][128][1024]
  bf16* attnB  = hiddenB;                      // alias: hiddenB dead after gemm1

  cvt_f32_bf16<<<8192, 256, 0, stream>>>(hidden, hiddenB, 2097152);
  transpose_cvt<<<dim3(192, 128), 256, 0, stream>>>(wqkv, wqkvT, 4096, 6144);
  transpose_cvt<<<dim3(128, 128), 256, 0, stream>>>(wo, woT, 4096, 4096);
  gemm_8ph<256, 1><<<dim3(192), 512, 131072, stream>>>(hiddenB, wqkvT, qkvB, 6144, 4096, 24);
  rope_reshape<<<2048, 256, 0, stream>>>(qkvB, cosp, sinp, Qb, Kb, VTb);
  flash_attn<<<dim3(512), 256, 0, stream>>>(Qb, Kb, VTb, attnB);
  gemm_8ph<128, 0><<<dim3(256), 512, 98304, stream>>>(attnB, woT, out, 4096, 4096, 32);
}

// Round 6
// 399.452 us; speedup vs baseline: 1.0165x; 1.0165x over previous
//
#include <hip/hip_runtime.h>
#include <hip/hip_bf16.h>

typedef __bf16 bf16;
typedef __attribute__((ext_vector_type(2))) __bf16 bf16x2;
typedef __attribute__((ext_vector_type(4))) __bf16 bf16x4;
typedef __attribute__((ext_vector_type(8))) __bf16 bf16x8;
typedef __attribute__((ext_vector_type(4))) float f32x4;

#define NB 2
#define SEQ 1024
#define HIDN 4096
#define NH 32
#define NKV 8
#define DH 128
#define QKV_N 6144
static constexpr float SCALE = 0.08838834764831845f;  // 1/sqrt(128)

#define MFMA(a, b, c) __builtin_amdgcn_mfma_f32_16x16x32_bf16((a), (b), (c), 0, 0, 0)

__device__ __forceinline__ void async16(const void* g, void* l) {
  __builtin_amdgcn_global_load_lds(
      (const __attribute__((address_space(1))) unsigned int*)g,
      (__attribute__((address_space(3))) unsigned int*)l,
      16, 0, 0);
}

__device__ __forceinline__ void barrier_raw() {
  asm volatile("" ::: "memory");
  __builtin_amdgcn_s_barrier();
  asm volatile("" ::: "memory");
}
#define VMCNT(n) asm volatile("s_waitcnt vmcnt(" #n ")" ::: "memory")

// ---------------- f32 -> bf16 convert (vector) ----------------
__global__ __launch_bounds__(256) void cvt_f32_bf16(const float* __restrict__ src,
                                                    bf16* __restrict__ dst, int n4) {
  int i = blockIdx.x * 256 + threadIdx.x;
  if (i >= n4) return;
  const float4 v = ((const float4*)src)[i];
  bf16x4 o = {(bf16)v.x, (bf16)v.y, (bf16)v.z, (bf16)v.w};
  ((bf16x4*)dst)[i] = o;
}

// ---------------- transpose + convert: dst[N][K] = (bf16)src[K][N] ----------------
__global__ __launch_bounds__(256) void transpose_cvt(const float* __restrict__ src,
                                                     bf16* __restrict__ dst, int R, int C) {
  __shared__ float tl[32][33];
  const int j0 = blockIdx.x * 32, i0 = blockIdx.y * 32;
  const int tr = threadIdx.x >> 5, tc = threadIdx.x & 31;
#pragma unroll
  for (int p = 0; p < 4; ++p)
    tl[tr + p * 8][tc] = src[(size_t)(i0 + tr + p * 8) * C + j0 + tc];
  __syncthreads();
#pragma unroll
  for (int p = 0; p < 4; ++p)
    dst[(size_t)(j0 + tr + p * 8) * R + i0 + tc] = (bf16)tl[tc][tr + p * 8];
}

// ======== GEMM1: 256x256 tile, BK=64, 512 thr (8 waves 2Mx4N), 2 LDS buffers ========
// Phases (kk, n-half): A-frags read ONCE per kk (register reuse across n-half phases),
// stage issues front-loaded (full half-tile at p0/p1), counted vmcnt with 4-phase leads:
//   p1-end VMCNT(8)  -> H(t,1) landed (issued t-1.p1)
//   p3-end VMCNT(4)  -> H(t+1,0) landed (issued t.p0)
template <int OUT_BF16>
__global__ __launch_bounds__(512, 2) void gemm_q(const bf16* __restrict__ A,
                                                 const bf16* __restrict__ BT,
                                                 void* __restrict__ Cout,
                                                 int N, int K, int mcnt) {
  extern __shared__ char smem[];
  constexpr int CA = 256 * 32 * 2;    // 16 KiB A chunk per kk-half
  constexpr int CB = 256 * 32 * 2;    // 16 KiB B chunk per kk-half
  constexpr int BUF = 2 * (CA + CB);  // 64 KiB per K-tile
  const int t = threadIdx.x, lane = t & 63, w = t >> 6;
  const int l16 = lane & 15, lq = lane >> 4;
  const int wm = w >> 2, wn = w & 3;

  const int nwg = gridDim.x;  // divisible by 8
  const int lin = ((int)blockIdx.x & 7) * (nwg >> 3) + ((int)blockIdx.x >> 3);
  const int m0 = (lin % mcnt) * 256, n0 = (lin / mcnt) * 256;  // m-inner per XCD chunk

  const int srow = t >> 2;
  const int sslot = (t & 3) ^ ((srow >> 1) & 3);
  const bf16* gA0 = A + (size_t)(m0 + srow) * K + sslot * 8;
  const bf16* gA1 = A + (size_t)(m0 + srow + 128) * K + sslot * 8;
  const bf16* gB0 = BT + (size_t)(n0 + srow) * K + sslot * 8;
  const bf16* gB1 = BT + (size_t)(n0 + srow + 128) * K + sslot * 8;

  int abyte[8], bbyte[4];
#pragma unroll
  for (int f = 0; f < 8; ++f) {
    const int r = wm * 128 + f * 16 + l16;
    abyte[f] = r * 64 + ((lq ^ ((r >> 1) & 3)) << 4);
  }
#pragma unroll
  for (int j = 0; j < 4; ++j) {
    const int r = wn * 64 + j * 16 + l16;
    bbyte[j] = r * 64 + ((lq ^ ((r >> 1) & 3)) << 4);
  }

  auto stageH = [&](int bsel, int kt, int kh) {  // full half-tile: A + B, 4 loads/thread
    char* d = smem + bsel * BUF + kh * (CA + CB) + t * 16;
    const int ko = kt * 64 + kh * 32;
    async16(gA0 + ko, d);
    async16(gA1 + ko, d + 8192);
    async16(gB0 + ko, d + CA);
    async16(gB1 + ko, d + CA + 8192);
  };

  f32x4 acc[8][4] = {};
  const int NT = K >> 6;

  stageH(0, 0, 0);
  stageH(0, 0, 1);
  VMCNT(4);
  barrier_raw();

  for (int kt = 0; kt < NT; ++kt) {
    const char* bc = smem + (kt & 1) * BUF;
    const int nb = (kt + 1) & 1;
    const bool pf = (kt + 1 < NT);
    {  // ---- kk = 0 ----
      const char* kb = bc;
      bf16x8 aR[8];
#pragma unroll
      for (int f = 0; f < 8; ++f) aR[f] = *(const bf16x8*)(kb + abyte[f]);
      {  // phase p0: n-half 0
        bf16x8 b0 = *(const bf16x8*)(kb + CA + bbyte[0]);
        bf16x8 b1 = *(const bf16x8*)(kb + CA + bbyte[1]);
        if (pf) stageH(nb, kt + 1, 0);
        barrier_raw();
        __builtin_amdgcn_s_setprio(1);
#pragma unroll
        for (int f = 0; f < 8; ++f) {
          acc[f][0] = MFMA(aR[f], b0, acc[f][0]);
          acc[f][1] = MFMA(aR[f], b1, acc[f][1]);
        }
        __builtin_amdgcn_s_setprio(0);
        barrier_raw();
      }
      {  // phase p1: n-half 1 (A regs reused)
        bf16x8 b2 = *(const bf16x8*)(kb + CA + bbyte[2]);
        bf16x8 b3 = *(const bf16x8*)(kb + CA + bbyte[3]);
        if (pf) stageH(nb, kt + 1, 1);
        barrier_raw();
        __builtin_amdgcn_s_setprio(1);
#pragma unroll
        for (int f = 0; f < 8; ++f) {
          acc[f][2] = MFMA(aR[f], b2, acc[f][2]);
          acc[f][3] = MFMA(aR[f], b3, acc[f][3]);
        }
        __builtin_amdgcn_s_setprio(0);
        if (pf) { VMCNT(8); } else { VMCNT(0); }
        barrier_raw();
      }
    }
    {  // ---- kk = 1 ----
      const char* kb = bc + (CA + CB);
      bf16x8 aR[8];
#pragma unroll
      for (int f = 0; f < 8; ++f) aR[f] = *(const bf16x8*)(kb + abyte[f]);
      {  // phase p2 (pure compute, loads in flight)
        bf16x8 b0 = *(const bf16x8*)(kb + CA + bbyte[0]);
        bf16x8 b1 = *(const bf16x8*)(kb + CA + bbyte[1]);
        barrier_raw();
        __builtin_amdgcn_s_setprio(1);
#pragma unroll
        for (int f = 0; f < 8; ++f) {
          acc[f][0] = MFMA(aR[f], b0, acc[f][0]);
          acc[f][1] = MFMA(aR[f], b1, acc[f][1]);
        }
        __builtin_amdgcn_s_setprio(0);
        barrier_raw();
      }
      {  // phase p3
        bf16x8 b2 = *(const bf16x8*)(kb + CA + bbyte[2]);
        bf16x8 b3 = *(const bf16x8*)(kb + CA + bbyte[3]);
        barrier_raw();
        __builtin_amdgcn_s_setprio(1);
#pragma unroll
        for (int f = 0; f < 8; ++f) {
          acc[f][2] = MFMA(aR[f], b2, acc[f][2]);
          acc[f][3] = MFMA(aR[f], b3, acc[f][3]);
        }
        __builtin_amdgcn_s_setprio(0);
        if (pf) { VMCNT(4); }
        barrier_raw();
      }
    }
  }

#pragma unroll
  for (int f = 0; f < 8; ++f)
#pragma unroll
    for (int j = 0; j < 4; ++j)
#pragma unroll
      for (int r = 0; r < 4; ++r) {
        const int row = m0 + wm * 128 + f * 16 + lq * 4 + r;
        const int col = n0 + wn * 64 + j * 16 + l16;
        if (OUT_BF16)
          ((bf16*)Cout)[(size_t)row * N + col] = (bf16)acc[f][j][r];
        else
          ((float*)Cout)[(size_t)row * N + col] = acc[f][j][r];
      }
}

// ======== GEMM2: 128x256 tile, BK=64, 512 thr (8 waves 2Mx4N), 3 LDS buffers ========
// 2 phases/K-tile (one per kk-half): 8 ds_read + 16 MFMA. Stage t+2 -> 3-phase leads,
// uniform VMCNT(9) in steady state (3 half-tiles in flight), explicit tail drain.
template <int OUT_BF16>
__global__ __launch_bounds__(512, 2) void gemm_h(const bf16* __restrict__ A,
                                                 const bf16* __restrict__ BT,
                                                 void* __restrict__ Cout,
                                                 int N, int K, int mcnt) {
  extern __shared__ char smem[];
  constexpr int CA = 128 * 32 * 2;    // 8 KiB A chunk per kk-half
  constexpr int CB = 256 * 32 * 2;    // 16 KiB B chunk per kk-half
  constexpr int BUF = 2 * (CA + CB);  // 48 KiB per K-tile; x3 = 144 KiB
  const int t = threadIdx.x, lane = t & 63, w = t >> 6;
  const int l16 = lane & 15, lq = lane >> 4;
  const int wm = w >> 2, wn = w & 3;

  const int nwg = gridDim.x;
  const int lin = ((int)blockIdx.x & 7) * (nwg >> 3) + ((int)blockIdx.x >> 3);
  const int m0 = (lin % mcnt) * 128, n0 = (lin / mcnt) * 256;

  const int srow = t >> 2;
  const int sslot = (t & 3) ^ ((srow >> 1) & 3);
  const bf16* gA0 = A + (size_t)(m0 + srow) * K + sslot * 8;
  const bf16* gB0 = BT + (size_t)(n0 + srow) * K + sslot * 8;
  const bf16* gB1 = BT + (size_t)(n0 + srow + 128) * K + sslot * 8;

  int abyte[4], bbyte[4];
#pragma unroll
  for (int f = 0; f < 4; ++f) {
    const int r = wm * 64 + f * 16 + l16;
    abyte[f] = r * 64 + ((lq ^ ((r >> 1) & 3)) << 4);
  }
#pragma unroll
  for (int j = 0; j < 4; ++j) {
    const int r = wn * 64 + j * 16 + l16;
    bbyte[j] = r * 64 + ((lq ^ ((r >> 1) & 3)) << 4);
  }

  auto stage2 = [&](char* dstbuf, int kt, int kh) {  // 3 loads/thread
    char* d = dstbuf + kh * (CA + CB) + t * 16;
    const int ko = kt * 64 + kh * 32;
    async16(gA0 + ko, d);
    async16(gB0 + ko, d + CA);
    async16(gB1 + ko, d + CA + 8192);
  };

  f32x4 acc[4][4] = {};
  const int NT = K >> 6;

  char* c0 = smem;
  char* c1 = smem + BUF;
  char* c2 = smem + 2 * BUF;

  stage2(c0, 0, 0);
  stage2(c0, 0, 1);
  stage2(c1, 1, 0);
  stage2(c1, 1, 1);
  VMCNT(9);
  barrier_raw();

  for (int kt = 0; kt < NT; ++kt) {
    const bool pf2 = (kt + 2 < NT);
    const bool last = (kt + 1 >= NT);
#pragma unroll
    for (int kk = 0; kk < 2; ++kk) {
      const char* kb = c0 + kk * (CA + CB);
      bf16x8 aR[4], bR[4];
#pragma unroll
      for (int f = 0; f < 4; ++f) aR[f] = *(const bf16x8*)(kb + abyte[f]);
#pragma unroll
      for (int j = 0; j < 4; ++j) bR[j] = *(const bf16x8*)(kb + CA + bbyte[j]);
      if (pf2) stage2(c2, kt + 2, kk);
      barrier_raw();
      __builtin_amdgcn_s_setprio(1);
#pragma unroll
      for (int f = 0; f < 4; ++f)
#pragma unroll
        for (int j = 0; j < 4; ++j) acc[f][j] = MFMA(aR[f], bR[j], acc[f][j]);
      __builtin_amdgcn_s_setprio(0);
      if (kk == 0) {
        if (pf2) { VMCNT(9); } else if (!last) { VMCNT(6); } else { VMCNT(0); }
      } else {
        if (pf2) { VMCNT(9); } else if (!last) { VMCNT(3); }
      }
      barrier_raw();
    }
    char* tmp = c0;  // rotate
    c0 = c1;
    c1 = c2;
    c2 = tmp;
  }

#pragma unroll
  for (int f = 0; f < 4; ++f)
#pragma unroll
    for (int j = 0; j < 4; ++j)
#pragma unroll
      for (int r = 0; r < 4; ++r) {
        const int row = m0 + wm * 64 + f * 16 + lq * 4 + r;
        const int col = n0 + wn * 64 + j * 16 + l16;
        if (OUT_BF16)
          ((bf16*)Cout)[(size_t)row * N + col] = (bf16)acc[f][j][r];
        else
          ((float*)Cout)[(size_t)row * N + col] = acc[f][j][r];
      }
}

// ---------------- RoPE + reshape: qkv -> Q[b][h][s][d] (scaled), K[b][kv][s][d], VT[b][kv][d][s] ----------------
__global__ __launch_bounds__(256) void rope_reshape(const bf16* __restrict__ qkv,
                                                    const float* __restrict__ cosp,
                                                    const float* __restrict__ sinp,
                                                    bf16* __restrict__ Qo,
                                                    bf16* __restrict__ Ko,
                                                    bf16* __restrict__ VTo) {
  const int row = blockIdx.x;          // b*SEQ + s
  const int b = row >> 10, s = row & 1023;
  const bf16* src = qkv + (size_t)row * QKV_N;
  for (int p = threadIdx.x; p < QKV_N / 2; p += 256) {
    const int col = p * 2;
    bf16x2 x = *(const bf16x2*)&src[col];
    const float x1 = (float)x.x, x2 = (float)x.y;
    if (col < 4096) {
      const int h = col >> 7, d = col & 127, i = (col & 127) >> 1;
      const float c = cosp[s * 64 + i], sn = sinp[s * 64 + i];
      bf16x2 o = {(bf16)((x1 * c - x2 * sn) * SCALE), (bf16)((x1 * sn + x2 * c) * SCALE)};
      *(bf16x2*)&Qo[((size_t)(b * NH + h) * SEQ + s) * DH + d] = o;
    } else if (col < 5120) {
      const int idx = col - 4096;
      const int kvh = idx >> 7, d = idx & 127, i = (idx & 127) >> 1;
      const float c = cosp[s * 64 + i], sn = sinp[s * 64 + i];
      bf16x2 o = {(bf16)(x1 * c - x2 * sn), (bf16)(x1 * sn + x2 * c)};
      *(bf16x2*)&Ko[((size_t)(b * NKV + kvh) * SEQ + s) * DH + d] = o;
    } else {
      const int idx = col - 5120;
      const int kvh = idx >> 7, d = idx & 127;
      bf16* vbase = VTo + ((size_t)(b * NKV + kvh) * DH + d) * SEQ + s;
      vbase[0] = x.x;
      vbase[SEQ] = x.y;
    }
  }
}

// ---------------- causal GQA flash attention, paired q-tiles ----------------
__global__ __launch_bounds__(256, 2) void flash_attn(const bf16* __restrict__ Q,
                                                     const bf16* __restrict__ K,
                                                     const bf16* __restrict__ VT,
                                                     bf16* __restrict__ O) {
  const int lane = threadIdx.x & 63, w = threadIdx.x >> 6;
  const int l16 = lane & 15, lq = lane >> 4;
  const int p = blockIdx.x * 4 + w;  // 0..2047
  const int b = p >> 10, h = (p >> 5) & 31, t = p & 31;
  const int kvh = h >> 2;  // G = 4

  const bf16* Qb = Q + (size_t)(b * NH + h) * SEQ * DH;
  const bf16* Kb = K + (size_t)(b * NKV + kvh) * SEQ * DH;
  const bf16* Vb = VT + (size_t)(b * NKV + kvh) * DH * SEQ;

  const int qrA = t * 16, qrB = (63 - t) * 16;
  const int nA = t / 4 + 1, nB = (63 - t) / 4 + 1;

  __shared__ bf16 plds[4][2][16][72];

  bf16x8 qfA[4], qfB[4];
#pragma unroll
  for (int kk = 0; kk < 4; ++kk) {
    qfA[kk] = *(const bf16x8*)&Qb[(size_t)(qrA + l16) * DH + kk * 32 + lq * 8];
    qfB[kk] = *(const bf16x8*)&Qb[(size_t)(qrB + l16) * DH + kk * 32 + lq * 8];
  }

  f32x4 accA[8] = {}, accB[8] = {};
  float mA[4], lA[4], mB[4], lB[4];
#pragma unroll
  for (int r = 0; r < 4; ++r) {
    mA[r] = mB[r] = -INFINITY;
    lA[r] = lB[r] = 0.f;
  }

  auto finish = [&](f32x4(&s)[4], float(&m)[4], float(&l)[4], f32x4(&acc)[8], int slot,
                    bool mask, int kv, int qr) {
    if (mask) {
#pragma unroll
      for (int nt = 0; nt < 4; ++nt)
#pragma unroll
        for (int r = 0; r < 4; ++r)
          if (kv * 64 + nt * 16 + l16 > qr + lq * 4 + r) s[nt][r] = -INFINITY;
    }
#pragma unroll
    for (int r = 0; r < 4; ++r) {
      float mx = fmaxf(fmaxf(s[0][r], s[1][r]), fmaxf(s[2][r], s[3][r]));
#pragma unroll
      for (int off = 1; off < 16; off <<= 1) mx = fmaxf(mx, __shfl_xor(mx, off));
      const float mn = fmaxf(m[r], mx);
      const float corr = __expf(m[r] - mn);
      m[r] = mn;
      float ps = 0.f;
#pragma unroll
      for (int nt = 0; nt < 4; ++nt) {
        const float pv = __expf(s[nt][r] - mn);
        s[nt][r] = pv;
        ps += pv;
      }
#pragma unroll
      for (int off = 1; off < 16; off <<= 1) ps += __shfl_xor(ps, off);
      l[r] = l[r] * corr + ps;
#pragma unroll
      for (int j = 0; j < 8; ++j) acc[j][r] *= corr;
    }
#pragma unroll
    for (int nt = 0; nt < 4; ++nt)
#pragma unroll
      for (int r = 0; r < 4; ++r)
        plds[w][slot][lq * 4 + r][nt * 16 + l16] = (bf16)s[nt][r];
  };

  int kv = 0;
  for (; kv < nA; ++kv) {
    f32x4 sA[4] = {}, sB[4] = {};
    const bf16* kbase = &Kb[(size_t)(kv * 64 + l16) * DH + lq * 8];
#pragma unroll
    for (int nt = 0; nt < 4; ++nt) {
      const bf16* kr = kbase + (size_t)nt * 16 * DH;
      bf16x8 k0 = *(const bf16x8*)kr;
      bf16x8 k1 = *(const bf16x8*)(kr + 32);
      bf16x8 k2 = *(const bf16x8*)(kr + 64);
      bf16x8 k3 = *(const bf16x8*)(kr + 96);
      sA[nt] = MFMA(qfA[0], k0, sA[nt]);
      sB[nt] = MFMA(qfB[0], k0, sB[nt]);
      sA[nt] = MFMA(qfA[1], k1, sA[nt]);
      sB[nt] = MFMA(qfB[1], k1, sB[nt]);
      sA[nt] = MFMA(qfA[2], k2, sA[nt]);
      sB[nt] = MFMA(qfB[2], k2, sB[nt]);
      sA[nt] = MFMA(qfA[3], k3, sA[nt]);
      sB[nt] = MFMA(qfB[3], k3, sB[nt]);
    }
    finish(sA, mA, lA, accA, 0, kv == nA - 1, kv, qrA);
    finish(sB, mB, lB, accB, 1, false, kv, qrB);
    bf16x8 pA0 = *(const bf16x8*)&plds[w][0][l16][lq * 8];
    bf16x8 pA1 = *(const bf16x8*)&plds[w][0][l16][32 + lq * 8];
    bf16x8 pB0 = *(const bf16x8*)&plds[w][1][l16][lq * 8];
    bf16x8 pB1 = *(const bf16x8*)&plds[w][1][l16][32 + lq * 8];
    const bf16* vbase = &Vb[(size_t)l16 * SEQ + kv * 64 + lq * 8];
#pragma unroll
    for (int j = 0; j < 8; ++j) {
      const bf16* vr = vbase + (size_t)j * 16 * SEQ;
      bf16x8 v0 = *(const bf16x8*)vr;
      bf16x8 v1 = *(const bf16x8*)(vr + 32);
      accA[j] = MFMA(pA0, v0, accA[j]);
      accB[j] = MFMA(pB0, v0, accB[j]);
      accA[j] = MFMA(pA1, v1, accA[j]);
      accB[j] = MFMA(pB1, v1, accB[j]);
    }
  }
  for (; kv < nB; ++kv) {
    f32x4 sB[4] = {};
    const bf16* kbase = &Kb[(size_t)(kv * 64 + l16) * DH + lq * 8];
#pragma unroll
    for (int nt = 0; nt < 4; ++nt) {
      const bf16* kr = kbase + (size_t)nt * 16 * DH;
      bf16x8 k0 = *(const bf16x8*)kr;
      bf16x8 k1 = *(const bf16x8*)(kr + 32);
      bf16x8 k2 = *(const bf16x8*)(kr + 64);
      bf16x8 k3 = *(const bf16x8*)(kr + 96);
      sB[nt] = MFMA(qfB[0], k0, sB[nt]);
      sB[nt] = MFMA(qfB[1], k1, sB[nt]);
      sB[nt] = MFMA(qfB[2], k2, sB[nt]);
      sB[nt] = MFMA(qfB[3], k3, sB[nt]);
    }
    finish(sB, mB, lB, accB, 1, kv == nB - 1, kv, qrB);
    bf16x8 pB0 = *(const bf16x8*)&plds[w][1][l16][lq * 8];
    bf16x8 pB1 = *(const bf16x8*)&plds[w][1][l16][32 + lq * 8];
    const bf16* vbase = &Vb[(size_t)l16 * SEQ + kv * 64 + lq * 8];
#pragma unroll
    for (int j = 0; j < 8; ++j) {
      const bf16* vr = vbase + (size_t)j * 16 * SEQ;
      bf16x8 v0 = *(const bf16x8*)vr;
      bf16x8 v1 = *(const bf16x8*)(vr + 32);
      accB[j] = MFMA(pB0, v0, accB[j]);
      accB[j] = MFMA(pB1, v1, accB[j]);
    }
  }

  auto wout = [&](f32x4(&acc)[8], float(&l)[4], int qr) {
#pragma unroll
    for (int r = 0; r < 4; ++r) {
      const float inv = 1.f / l[r];
      const size_t orow = ((size_t)b * SEQ + qr + lq * 4 + r) * HIDN + h * DH;
#pragma unroll
      for (int j = 0; j < 8; ++j) O[orow + j * 16 + l16] = (bf16)(acc[j][r] * inv);
    }
  };
  wout(accA, lA, qrA);
  wout(accB, lB, qrB);
}

extern "C" void kernel_launch(void* const* d_in, const int* in_sizes, int n_in,
                              void* d_out, int out_size, void* d_ws, size_t ws_size,
                              hipStream_t stream) {
  const float* hidden = (const float*)d_in[0];
  const float* cosp = (const float*)d_in[1];
  const float* sinp = (const float*)d_in[2];
  const float* wqkv = (const float*)d_in[3];
  const float* wo = (const float*)d_in[4];
  float* out = (float*)d_out;

  char* ws = (char*)d_ws;
  bf16* hiddenB = (bf16*)(ws);                 // 16,777,216   [2048][4096]
  bf16* wqkvT  = (bf16*)(ws + 16777216);       // 50,331,648   [6144][4096]
  bf16* woT    = (bf16*)(ws + 67108864);       // 33,554,432   [4096][4096]
  bf16* qkvB   = (bf16*)(ws + 100663296);      // 25,165,824   [2048][6144]
  bf16* Qb     = (bf16*)(ws + 125829120);      // 16,777,216   [2][32][1024][128]
  bf16* Kb     = (bf16*)(ws + 142606336);      //  4,194,304   [2][8][1024][128]
  bf16* VTb    = (bf16*)(ws + 146800640);      //  4,194,304   [2][8][128][1024]
  bf16* attnB  = hiddenB;                      // alias: hiddenB dead after gemm1

  cvt_f32_bf16<<<8192, 256, 0, stream>>>(hidden, hiddenB, 2097152);
  transpose_cvt<<<dim3(192, 128), 256, 0, stream>>>(wqkv, wqkvT, 4096, 6144);
  transpose_cvt<<<dim3(128, 128), 256, 0, stream>>>(wo, woT, 4096, 4096);
  gemm_q<1><<<dim3(192), 512, 131072, stream>>>(hiddenB, wqkvT, qkvB, 6144, 4096, 8);
  rope_reshape<<<2048, 256, 0, stream>>>(qkvB, cosp, sinp, Qb, Kb, VTb);
  flash_attn<<<dim3(512), 256, 0, stream>>>(Qb, Kb, VTb, attnB);
  gemm_h<0><<<dim3(256), 512, 147456, stream>>>(attnB, woT, out, 4096, 4096, 16);
}

// Round 7
// 369.589 us; speedup vs baseline: 1.0987x; 1.0808x over previous
//
#include <hip/hip_runtime.h>
#include <hip/hip_bf16.h>

typedef __bf16 bf16;
typedef __attribute__((ext_vector_type(2))) __bf16 bf16x2;
typedef __attribute__((ext_vector_type(4))) __bf16 bf16x4;
typedef __attribute__((ext_vector_type(8))) __bf16 bf16x8;
typedef __attribute__((ext_vector_type(4))) float f32x4;

#define NB 2
#define SEQ 1024
#define HIDN 4096
#define NH 32
#define NKV 8
#define DH 128
#define QKV_N 6144
static constexpr float SCALE = 0.08838834764831845f;  // 1/sqrt(128)

#define MFMA(a, b, c) __builtin_amdgcn_mfma_f32_16x16x32_bf16((a), (b), (c), 0, 0, 0)

__device__ __forceinline__ void async16(const void* g, void* l) {
  __builtin_amdgcn_global_load_lds(
      (const __attribute__((address_space(1))) unsigned int*)g,
      (__attribute__((address_space(3))) unsigned int*)l,
      16, 0, 0);
}

__device__ __forceinline__ void barrier_raw() {
  asm volatile("" ::: "memory");
  __builtin_amdgcn_s_barrier();
  asm volatile("" ::: "memory");
}
#define VMCNT(n) asm volatile("s_waitcnt vmcnt(" #n ")" ::: "memory")

// ---------------- f32 -> bf16 convert (vector) ----------------
__global__ __launch_bounds__(256) void cvt_f32_bf16(const float* __restrict__ src,
                                                    bf16* __restrict__ dst, int n4) {
  int i = blockIdx.x * 256 + threadIdx.x;
  if (i >= n4) return;
  const float4 v = ((const float4*)src)[i];
  bf16x4 o = {(bf16)v.x, (bf16)v.y, (bf16)v.z, (bf16)v.w};
  ((bf16x4*)dst)[i] = o;
}

// ---------------- transpose + convert: dst[N][K] = (bf16)src[K][N] ----------------
__global__ __launch_bounds__(256) void transpose_cvt(const float* __restrict__ src,
                                                     bf16* __restrict__ dst, int R, int C) {
  __shared__ float tl[32][33];
  const int j0 = blockIdx.x * 32, i0 = blockIdx.y * 32;
  const int tr = threadIdx.x >> 5, tc = threadIdx.x & 31;
#pragma unroll
  for (int p = 0; p < 4; ++p)
    tl[tr + p * 8][tc] = src[(size_t)(i0 + tr + p * 8) * C + j0 + tc];
  __syncthreads();
#pragma unroll
  for (int p = 0; p < 4; ++p)
    dst[(size_t)(j0 + tr + p * 8) * R + i0 + tc] = (bf16)tl[tc][tr + p * 8];
}

// ======== Deep-pipelined bf16 GEMM, BM=128, BK=32, 4 LDS K-tile buffers ========
// C[M][N] = A[M][K] * BT[N][K]^T.  512 thr = 8 waves (2M x 4N); per-wave C = 64 x BN/4.
// Grid = (M/128)*(N/BN) = 256 blocks exactly (full machine).  2 phases per K-tile:
//   p0: read A-frags (reused) + first FN/2 B-frags; issue stage units 0..1 of kt+3;
//       barrier; 4*FN/2 MFMA.
//   p1: read last FN/2 B-frags; issue remaining stage units of kt+3;
//       VMCNT(2*LTOT) (counted, never 0 mid-loop); barrier; 4*FN/2 MFMA.
// Ledger: wait at p1(kt) leaves tiles kt+2,kt+3 in flight -> kt+1 certified for its p0.
// Lead(issue->wait) = 5-6 phases (~1.5 K-tiles) > HBM latency.  Swizzle: 64B rows,
// 16B slot ^= (row>>1)&3, pre-swizzled global source (0 bank conflicts, verified R3-R6).
template <int BN, int OUT_BF16>
__global__ __launch_bounds__(512, 2) void gemm_dp(const bf16* __restrict__ A,
                                                  const bf16* __restrict__ BT,
                                                  void* __restrict__ Cout,
                                                  int N, int K) {
  extern __shared__ char smem[];
  constexpr int CA = 128 * 32 * 2;       // 8 KiB A chunk
  constexpr int CB = BN * 32 * 2;        // 24 / 16 KiB B chunk
  constexpr int BUF = CA + CB;           // one K-tile buffer
  constexpr int LTOT = 1 + BN / 128;     // stage instr / thread / K-tile (4 or 3)
  constexpr int FN = BN / 64;            // B frags per wave (6 or 4)
  constexpr int FNH = FN / 2;
  const int t = threadIdx.x, lane = t & 63, w = t >> 6;
  const int l16 = lane & 15, lq = lane >> 4;
  const int wm = w >> 2, wn = w & 3;

  const int nwg = gridDim.x;  // 256
  const int lin = ((int)blockIdx.x & 7) * (nwg >> 3) + ((int)blockIdx.x >> 3);
  const int m0 = (lin & 15) * 128;  // m-inner: each XCD chunk reuses its B panels
  const int n0 = (lin >> 4) * BN;

  // staging sources (pre-swizzled global, linear LDS dest). LDS row of thread t in
  // every 8KB unit = t>>2; swizzle xor = ((t>>3)&3) uniformly (unit base rows %4==0).
  const int sslot = (t & 3) ^ ((t >> 3) & 3);
  const bf16* gsrc[LTOT];
  gsrc[0] = A + (size_t)(m0 + (t >> 2)) * K + sslot * 8;
#pragma unroll
  for (int u = 1; u < LTOT; ++u)
    gsrc[u] = BT + (size_t)(n0 + (u - 1) * 128 + (t >> 2)) * K + sslot * 8;

  // swizzled fragment byte offsets
  int abyte[4], bbyte[FN];
#pragma unroll
  for (int f = 0; f < 4; ++f) {
    const int r = wm * 64 + f * 16 + l16;
    abyte[f] = r * 64 + ((lq ^ ((r >> 1) & 3)) << 4);
  }
#pragma unroll
  for (int j = 0; j < FN; ++j) {
    const int r = wn * (BN / 4) + j * 16 + l16;
    bbyte[j] = CA + r * 64 + ((lq ^ ((r >> 1) & 3)) << 4);
  }

  auto stage_unit = [&](int kt, int u) {
    char* d = smem + (kt & 3) * BUF + u * 8192 + t * 16;
    async16(gsrc[u] + (size_t)kt * 32, d);
  };

  f32x4 acc[4][FN] = {};
  const int NT = K >> 5;  // 128

  // prologue: stage tiles 0,1,2; certify tile 0
#pragma unroll
  for (int kt = 0; kt < 3; ++kt)
#pragma unroll
    for (int u = 0; u < LTOT; ++u) stage_unit(kt, u);
  if constexpr (LTOT == 4) { VMCNT(8); } else { VMCNT(6); }
  barrier_raw();

  for (int kt = 0; kt < NT; ++kt) {
    const char* buf = smem + (kt & 3) * BUF;
    const bool pf = (kt + 3 < NT);
    // ---- phase 0 ----
    bf16x8 af[4], bf0[FNH];
#pragma unroll
    for (int f = 0; f < 4; ++f) af[f] = *(const bf16x8*)(buf + abyte[f]);
#pragma unroll
    for (int j = 0; j < FNH; ++j) bf0[j] = *(const bf16x8*)(buf + bbyte[j]);
    if (pf) {
      stage_unit(kt + 3, 0);
      stage_unit(kt + 3, 1);
    }
    barrier_raw();
    __builtin_amdgcn_s_setprio(1);
#pragma unroll
    for (int f = 0; f < 4; ++f)
#pragma unroll
      for (int j = 0; j < FNH; ++j) acc[f][j] = MFMA(af[f], bf0[j], acc[f][j]);
    __builtin_amdgcn_s_setprio(0);
    // ---- phase 1 ----
    bf16x8 bf1[FN - FNH];
#pragma unroll
    for (int j = 0; j < FN - FNH; ++j) bf1[j] = *(const bf16x8*)(buf + bbyte[FNH + j]);
    if (pf) {
#pragma unroll
      for (int u = 2; u < LTOT; ++u) stage_unit(kt + 3, u);
    }
    if (pf) {
      if constexpr (LTOT == 4) { VMCNT(8); } else { VMCNT(6); }
    } else if (kt + 2 < NT) {
      if constexpr (LTOT == 4) { VMCNT(4); } else { VMCNT(3); }
    } else {
      VMCNT(0);
    }
    barrier_raw();
    __builtin_amdgcn_s_setprio(1);
#pragma unroll
    for (int f = 0; f < 4; ++f)
#pragma unroll
      for (int j = 0; j < FN - FNH; ++j)
        acc[f][FNH + j] = MFMA(af[f], bf1[j], acc[f][FNH + j]);
    __builtin_amdgcn_s_setprio(0);
  }

#pragma unroll
  for (int f = 0; f < 4; ++f)
#pragma unroll
    for (int j = 0; j < FN; ++j)
#pragma unroll
      for (int r = 0; r < 4; ++r) {
        const int row = m0 + wm * 64 + f * 16 + lq * 4 + r;
        const int col = n0 + wn * (BN / 4) + j * 16 + l16;
        if (OUT_BF16)
          ((bf16*)Cout)[(size_t)row * N + col] = (bf16)acc[f][j][r];
        else
          ((float*)Cout)[(size_t)row * N + col] = acc[f][j][r];
      }
}

// ---------------- RoPE + reshape: qkv -> Q[b][h][s][d] (scaled), K[b][kv][s][d], VT[b][kv][d][s] ----------------
__global__ __launch_bounds__(256) void rope_reshape(const bf16* __restrict__ qkv,
                                                    const float* __restrict__ cosp,
                                                    const float* __restrict__ sinp,
                                                    bf16* __restrict__ Qo,
                                                    bf16* __restrict__ Ko,
                                                    bf16* __restrict__ VTo) {
  const int row = blockIdx.x;          // b*SEQ + s
  const int b = row >> 10, s = row & 1023;
  const bf16* src = qkv + (size_t)row * QKV_N;
  for (int p = threadIdx.x; p < QKV_N / 2; p += 256) {
    const int col = p * 2;
    bf16x2 x = *(const bf16x2*)&src[col];
    const float x1 = (float)x.x, x2 = (float)x.y;
    if (col < 4096) {
      const int h = col >> 7, d = col & 127, i = (col & 127) >> 1;
      const float c = cosp[s * 64 + i], sn = sinp[s * 64 + i];
      bf16x2 o = {(bf16)((x1 * c - x2 * sn) * SCALE), (bf16)((x1 * sn + x2 * c) * SCALE)};
      *(bf16x2*)&Qo[((size_t)(b * NH + h) * SEQ + s) * DH + d] = o;
    } else if (col < 5120) {
      const int idx = col - 4096;
      const int kvh = idx >> 7, d = idx & 127, i = (idx & 127) >> 1;
      const float c = cosp[s * 64 + i], sn = sinp[s * 64 + i];
      bf16x2 o = {(bf16)(x1 * c - x2 * sn), (bf16)(x1 * sn + x2 * c)};
      *(bf16x2*)&Ko[((size_t)(b * NKV + kvh) * SEQ + s) * DH + d] = o;
    } else {
      const int idx = col - 5120;
      const int kvh = idx >> 7, d = idx & 127;
      bf16* vbase = VTo + ((size_t)(b * NKV + kvh) * DH + d) * SEQ + s;
      vbase[0] = x.x;
      vbase[SEQ] = x.y;
    }
  }
}

// ---------------- causal GQA flash attention, paired q-tiles ----------------
__global__ __launch_bounds__(256, 2) void flash_attn(const bf16* __restrict__ Q,
                                                     const bf16* __restrict__ K,
                                                     const bf16* __restrict__ VT,
                                                     bf16* __restrict__ O) {
  const int lane = threadIdx.x & 63, w = threadIdx.x >> 6;
  const int l16 = lane & 15, lq = lane >> 4;
  const int p = blockIdx.x * 4 + w;  // 0..2047
  const int b = p >> 10, h = (p >> 5) & 31, t = p & 31;
  const int kvh = h >> 2;  // G = 4

  const bf16* Qb = Q + (size_t)(b * NH + h) * SEQ * DH;
  const bf16* Kb = K + (size_t)(b * NKV + kvh) * SEQ * DH;
  const bf16* Vb = VT + (size_t)(b * NKV + kvh) * DH * SEQ;

  const int qrA = t * 16, qrB = (63 - t) * 16;
  const int nA = t / 4 + 1, nB = (63 - t) / 4 + 1;

  __shared__ bf16 plds[4][2][16][72];

  bf16x8 qfA[4], qfB[4];
#pragma unroll
  for (int kk = 0; kk < 4; ++kk) {
    qfA[kk] = *(const bf16x8*)&Qb[(size_t)(qrA + l16) * DH + kk * 32 + lq * 8];
    qfB[kk] = *(const bf16x8*)&Qb[(size_t)(qrB + l16) * DH + kk * 32 + lq * 8];
  }

  f32x4 accA[8] = {}, accB[8] = {};
  float mA[4], lA[4], mB[4], lB[4];
#pragma unroll
  for (int r = 0; r < 4; ++r) {
    mA[r] = mB[r] = -INFINITY;
    lA[r] = lB[r] = 0.f;
  }

  auto finish = [&](f32x4(&s)[4], float(&m)[4], float(&l)[4], f32x4(&acc)[8], int slot,
                    bool mask, int kv, int qr) {
    if (mask) {
#pragma unroll
      for (int nt = 0; nt < 4; ++nt)
#pragma unroll
        for (int r = 0; r < 4; ++r)
          if (kv * 64 + nt * 16 + l16 > qr + lq * 4 + r) s[nt][r] = -INFINITY;
    }
#pragma unroll
    for (int r = 0; r < 4; ++r) {
      float mx = fmaxf(fmaxf(s[0][r], s[1][r]), fmaxf(s[2][r], s[3][r]));
#pragma unroll
      for (int off = 1; off < 16; off <<= 1) mx = fmaxf(mx, __shfl_xor(mx, off));
      const float mn = fmaxf(m[r], mx);
      const float corr = __expf(m[r] - mn);
      m[r] = mn;
      float ps = 0.f;
#pragma unroll
      for (int nt = 0; nt < 4; ++nt) {
        const float pv = __expf(s[nt][r] - mn);
        s[nt][r] = pv;
        ps += pv;
      }
#pragma unroll
      for (int off = 1; off < 16; off <<= 1) ps += __shfl_xor(ps, off);
      l[r] = l[r] * corr + ps;
#pragma unroll
      for (int j = 0; j < 8; ++j) acc[j][r] *= corr;
    }
#pragma unroll
    for (int nt = 0; nt < 4; ++nt)
#pragma unroll
      for (int r = 0; r < 4; ++r)
        plds[w][slot][lq * 4 + r][nt * 16 + l16] = (bf16)s[nt][r];
  };

  int kv = 0;
  for (; kv < nA; ++kv) {
    f32x4 sA[4] = {}, sB[4] = {};
    const bf16* kbase = &Kb[(size_t)(kv * 64 + l16) * DH + lq * 8];
#pragma unroll
    for (int nt = 0; nt < 4; ++nt) {
      const bf16* kr = kbase + (size_t)nt * 16 * DH;
      bf16x8 k0 = *(const bf16x8*)kr;
      bf16x8 k1 = *(const bf16x8*)(kr + 32);
      bf16x8 k2 = *(const bf16x8*)(kr + 64);
      bf16x8 k3 = *(const bf16x8*)(kr + 96);
      sA[nt] = MFMA(qfA[0], k0, sA[nt]);
      sB[nt] = MFMA(qfB[0], k0, sB[nt]);
      sA[nt] = MFMA(qfA[1], k1, sA[nt]);
      sB[nt] = MFMA(qfB[1], k1, sB[nt]);
      sA[nt] = MFMA(qfA[2], k2, sA[nt]);
      sB[nt] = MFMA(qfB[2], k2, sB[nt]);
      sA[nt] = MFMA(qfA[3], k3, sA[nt]);
      sB[nt] = MFMA(qfB[3], k3, sB[nt]);
    }
    finish(sA, mA, lA, accA, 0, kv == nA - 1, kv, qrA);
    finish(sB, mB, lB, accB, 1, false, kv, qrB);
    bf16x8 pA0 = *(const bf16x8*)&plds[w][0][l16][lq * 8];
    bf16x8 pA1 = *(const bf16x8*)&plds[w][0][l16][32 + lq * 8];
    bf16x8 pB0 = *(const bf16x8*)&plds[w][1][l16][lq * 8];
    bf16x8 pB1 = *(const bf16x8*)&plds[w][1][l16][32 + lq * 8];
    const bf16* vbase = &Vb[(size_t)l16 * SEQ + kv * 64 + lq * 8];
#pragma unroll
    for (int j = 0; j < 8; ++j) {
      const bf16* vr = vbase + (size_t)j * 16 * SEQ;
      bf16x8 v0 = *(const bf16x8*)vr;
      bf16x8 v1 = *(const bf16x8*)(vr + 32);
      accA[j] = MFMA(pA0, v0, accA[j]);
      accB[j] = MFMA(pB0, v0, accB[j]);
      accA[j] = MFMA(pA1, v1, accA[j]);
      accB[j] = MFMA(pB1, v1, accB[j]);
    }
  }
  for (; kv < nB; ++kv) {
    f32x4 sB[4] = {};
    const bf16* kbase = &Kb[(size_t)(kv * 64 + l16) * DH + lq * 8];
#pragma unroll
    for (int nt = 0; nt < 4; ++nt) {
      const bf16* kr = kbase + (size_t)nt * 16 * DH;
      bf16x8 k0 = *(const bf16x8*)kr;
      bf16x8 k1 = *(const bf16x8*)(kr + 32);
      bf16x8 k2 = *(const bf16x8*)(kr + 64);
      bf16x8 k3 = *(const bf16x8*)(kr + 96);
      sB[nt] = MFMA(qfB[0], k0, sB[nt]);
      sB[nt] = MFMA(qfB[1], k1, sB[nt]);
      sB[nt] = MFMA(qfB[2], k2, sB[nt]);
      sB[nt] = MFMA(qfB[3], k3, sB[nt]);
    }
    finish(sB, mB, lB, accB, 1, kv == nB - 1, kv, qrB);
    bf16x8 pB0 = *(const bf16x8*)&plds[w][1][l16][lq * 8];
    bf16x8 pB1 = *(const bf16x8*)&plds[w][1][l16][32 + lq * 8];
    const bf16* vbase = &Vb[(size_t)l16 * SEQ + kv * 64 + lq * 8];
#pragma unroll
    for (int j = 0; j < 8; ++j) {
      const bf16* vr = vbase + (size_t)j * 16 * SEQ;
      bf16x8 v0 = *(const bf16x8*)vr;
      bf16x8 v1 = *(const bf16x8*)(vr + 32);
      accB[j] = MFMA(pB0, v0, accB[j]);
      accB[j] = MFMA(pB1, v1, accB[j]);
    }
  }

  auto wout = [&](f32x4(&acc)[8], float(&l)[4], int qr) {
#pragma unroll
    for (int r = 0; r < 4; ++r) {
      const float inv = 1.f / l[r];
      const size_t orow = ((size_t)b * SEQ + qr + lq * 4 + r) * HIDN + h * DH;
#pragma unroll
      for (int j = 0; j < 8; ++j) O[orow + j * 16 + l16] = (bf16)(acc[j][r] * inv);
    }
  };
  wout(accA, lA, qrA);
  wout(accB, lB, qrB);
}

extern "C" void kernel_launch(void* const* d_in, const int* in_sizes, int n_in,
                              void* d_out, int out_size, void* d_ws, size_t ws_size,
                              hipStream_t stream) {
  const float* hidden = (const float*)d_in[0];
  const float* cosp = (const float*)d_in[1];
  const float* sinp = (const float*)d_in[2];
  const float* wqkv = (const float*)d_in[3];
  const float* wo = (const float*)d_in[4];
  float* out = (float*)d_out;

  char* ws = (char*)d_ws;
  bf16* hiddenB = (bf16*)(ws);                 // 16,777,216   [2048][4096]
  bf16* wqkvT  = (bf16*)(ws + 16777216);       // 50,331,648   [6144][4096]
  bf16* woT    = (bf16*)(ws + 67108864);       // 33,554,432   [4096][4096]
  bf16* qkvB   = (bf16*)(ws + 100663296);      // 25,165,824   [2048][6144]
  bf16* Qb     = (bf16*)(ws + 125829120);      // 16,777,216   [2][32][1024][128]
  bf16* Kb     = (bf16*)(ws + 142606336);      //  4,194,304   [2][8][1024][128]
  bf16* VTb    = (bf16*)(ws + 146800640);      //  4,194,304   [2][8][128][1024]
  bf16* attnB  = hiddenB;                      // alias: hiddenB dead after gemm1

  cvt_f32_bf16<<<8192, 256, 0, stream>>>(hidden, hiddenB, 2097152);
  transpose_cvt<<<dim3(192, 128), 256, 0, stream>>>(wqkv, wqkvT, 4096, 6144);
  transpose_cvt<<<dim3(128, 128), 256, 0, stream>>>(wo, woT, 4096, 4096);
  gemm_dp<384, 1><<<dim3(256), 512, 131072, stream>>>(hiddenB, wqkvT, qkvB, 6144, 4096);
  rope_reshape<<<2048, 256, 0, stream>>>(qkvB, cosp, sinp, Qb, Kb, VTb);
  flash_attn<<<dim3(512), 256, 0, stream>>>(Qb, Kb, VTb, attnB);
  gemm_dp<256, 0><<<dim3(256), 512, 98304, stream>>>(attnB, woT, out, 4096, 4096);
}

// Round 8
// 297.461 us; speedup vs baseline: 1.3651x; 1.2425x over previous
//
#include <hip/hip_runtime.h>
#include <hip/hip_bf16.h>

typedef __bf16 bf16;
typedef __attribute__((ext_vector_type(2))) __bf16 bf16x2;
typedef __attribute__((ext_vector_type(4))) __bf16 bf16x4;
typedef __attribute__((ext_vector_type(8))) __bf16 bf16x8;
typedef __attribute__((ext_vector_type(4))) float f32x4;

#define NB 2
#define SEQ 1024
#define HIDN 4096
#define NH 32
#define NKV 8
#define DH 128
#define QKV_N 6144
static constexpr float SCALE = 0.08838834764831845f;  // 1/sqrt(128)

#define MFMA(a, b, c) __builtin_amdgcn_mfma_f32_16x16x32_bf16((a), (b), (c), 0, 0, 0)

__device__ __forceinline__ void async16(const void* g, void* l) {
  __builtin_amdgcn_global_load_lds(
      (const __attribute__((address_space(1))) unsigned int*)g,
      (__attribute__((address_space(3))) unsigned int*)l,
      16, 0, 0);
}

__device__ __forceinline__ void barrier_raw() {
  asm volatile("" ::: "memory");
  __builtin_amdgcn_s_barrier();
  asm volatile("" ::: "memory");
}
#define VMCNT(n) asm volatile("s_waitcnt vmcnt(" #n ")" ::: "memory")

// ---------------- f32 -> bf16 convert (vector) ----------------
__global__ __launch_bounds__(256) void cvt_f32_bf16(const float* __restrict__ src,
                                                    bf16* __restrict__ dst, int n4) {
  int i = blockIdx.x * 256 + threadIdx.x;
  if (i >= n4) return;
  const float4 v = ((const float4*)src)[i];
  bf16x4 o = {(bf16)v.x, (bf16)v.y, (bf16)v.z, (bf16)v.w};
  ((bf16x4*)dst)[i] = o;
}

// ---------------- transpose + convert: dst[N][K] = (bf16)src[K][N] ----------------
__global__ __launch_bounds__(256) void transpose_cvt(const float* __restrict__ src,
                                                     bf16* __restrict__ dst, int R, int C) {
  __shared__ float tl[32][33];
  const int j0 = blockIdx.x * 32, i0 = blockIdx.y * 32;
  const int tr = threadIdx.x >> 5, tc = threadIdx.x & 31;
#pragma unroll
  for (int p = 0; p < 4; ++p)
    tl[tr + p * 8][tc] = src[(size_t)(i0 + tr + p * 8) * C + j0 + tc];
  __syncthreads();
#pragma unroll
  for (int p = 0; p < 4; ++p)
    dst[(size_t)(j0 + tr + p * 8) * R + i0 + tc] = (bf16)tl[tc][tr + p * 8];
}

// ======== Deep-pipelined bf16 GEMM, BM=128, BK=32, 4 LDS K-tile buffers (R7, kept) ====
template <int BN, int OUT_BF16>
__global__ __launch_bounds__(512, 2) void gemm_dp(const bf16* __restrict__ A,
                                                  const bf16* __restrict__ BT,
                                                  void* __restrict__ Cout,
                                                  int N, int K) {
  extern __shared__ char smem[];
  constexpr int CA = 128 * 32 * 2;
  constexpr int CB = BN * 32 * 2;
  constexpr int BUF = CA + CB;
  constexpr int LTOT = 1 + BN / 128;
  constexpr int FN = BN / 64;
  constexpr int FNH = FN / 2;
  const int t = threadIdx.x, lane = t & 63, w = t >> 6;
  const int l16 = lane & 15, lq = lane >> 4;
  const int wm = w >> 2, wn = w & 3;

  const int nwg = gridDim.x;  // 256
  const int lin = ((int)blockIdx.x & 7) * (nwg >> 3) + ((int)blockIdx.x >> 3);
  const int m0 = (lin & 15) * 128;
  const int n0 = (lin >> 4) * BN;

  const int sslot = (t & 3) ^ ((t >> 3) & 3);
  const bf16* gsrc[LTOT];
  gsrc[0] = A + (size_t)(m0 + (t >> 2)) * K + sslot * 8;
#pragma unroll
  for (int u = 1; u < LTOT; ++u)
    gsrc[u] = BT + (size_t)(n0 + (u - 1) * 128 + (t >> 2)) * K + sslot * 8;

  int abyte[4], bbyte[FN];
#pragma unroll
  for (int f = 0; f < 4; ++f) {
    const int r = wm * 64 + f * 16 + l16;
    abyte[f] = r * 64 + ((lq ^ ((r >> 1) & 3)) << 4);
  }
#pragma unroll
  for (int j = 0; j < FN; ++j) {
    const int r = wn * (BN / 4) + j * 16 + l16;
    bbyte[j] = CA + r * 64 + ((lq ^ ((r >> 1) & 3)) << 4);
  }

  auto stage_unit = [&](int kt, int u) {
    char* d = smem + (kt & 3) * BUF + u * 8192 + t * 16;
    async16(gsrc[u] + (size_t)kt * 32, d);
  };

  f32x4 acc[4][FN] = {};
  const int NT = K >> 5;

#pragma unroll
  for (int kt = 0; kt < 3; ++kt)
#pragma unroll
    for (int u = 0; u < LTOT; ++u) stage_unit(kt, u);
  if constexpr (LTOT == 4) { VMCNT(8); } else { VMCNT(6); }
  barrier_raw();

  for (int kt = 0; kt < NT; ++kt) {
    const char* buf = smem + (kt & 3) * BUF;
    const bool pf = (kt + 3 < NT);
    bf16x8 af[4], bf0[FNH];
#pragma unroll
    for (int f = 0; f < 4; ++f) af[f] = *(const bf16x8*)(buf + abyte[f]);
#pragma unroll
    for (int j = 0; j < FNH; ++j) bf0[j] = *(const bf16x8*)(buf + bbyte[j]);
    if (pf) {
      stage_unit(kt + 3, 0);
      stage_unit(kt + 3, 1);
    }
    barrier_raw();
    __builtin_amdgcn_s_setprio(1);
#pragma unroll
    for (int f = 0; f < 4; ++f)
#pragma unroll
      for (int j = 0; j < FNH; ++j) acc[f][j] = MFMA(af[f], bf0[j], acc[f][j]);
    __builtin_amdgcn_s_setprio(0);
    bf16x8 bf1[FN - FNH];
#pragma unroll
    for (int j = 0; j < FN - FNH; ++j) bf1[j] = *(const bf16x8*)(buf + bbyte[FNH + j]);
    if (pf) {
#pragma unroll
      for (int u = 2; u < LTOT; ++u) stage_unit(kt + 3, u);
    }
    if (pf) {
      if constexpr (LTOT == 4) { VMCNT(8); } else { VMCNT(6); }
    } else if (kt + 2 < NT) {
      if constexpr (LTOT == 4) { VMCNT(4); } else { VMCNT(3); }
    } else {
      VMCNT(0);
    }
    barrier_raw();
    __builtin_amdgcn_s_setprio(1);
#pragma unroll
    for (int f = 0; f < 4; ++f)
#pragma unroll
      for (int j = 0; j < FN - FNH; ++j)
        acc[f][FNH + j] = MFMA(af[f], bf1[j], acc[f][FNH + j]);
    __builtin_amdgcn_s_setprio(0);
  }

#pragma unroll
  for (int f = 0; f < 4; ++f)
#pragma unroll
    for (int j = 0; j < FN; ++j)
#pragma unroll
      for (int r = 0; r < 4; ++r) {
        const int row = m0 + wm * 64 + f * 16 + lq * 4 + r;
        const int col = n0 + wn * (BN / 4) + j * 16 + l16;
        if (OUT_BF16)
          ((bf16*)Cout)[(size_t)row * N + col] = (bf16)acc[f][j][r];
        else
          ((float*)Cout)[(size_t)row * N + col] = acc[f][j][r];
      }
}

// ---------------- RoPE + reshape ----------------
__global__ __launch_bounds__(256) void rope_reshape(const bf16* __restrict__ qkv,
                                                    const float* __restrict__ cosp,
                                                    const float* __restrict__ sinp,
                                                    bf16* __restrict__ Qo,
                                                    bf16* __restrict__ Ko,
                                                    bf16* __restrict__ VTo) {
  const int row = blockIdx.x;          // b*SEQ + s
  const int b = row >> 10, s = row & 1023;
  const bf16* src = qkv + (size_t)row * QKV_N;
  for (int p = threadIdx.x; p < QKV_N / 2; p += 256) {
    const int col = p * 2;
    bf16x2 x = *(const bf16x2*)&src[col];
    const float x1 = (float)x.x, x2 = (float)x.y;
    if (col < 4096) {
      const int h = col >> 7, d = col & 127, i = (col & 127) >> 1;
      const float c = cosp[s * 64 + i], sn = sinp[s * 64 + i];
      bf16x2 o = {(bf16)((x1 * c - x2 * sn) * SCALE), (bf16)((x1 * sn + x2 * c) * SCALE)};
      *(bf16x2*)&Qo[((size_t)(b * NH + h) * SEQ + s) * DH + d] = o;
    } else if (col < 5120) {
      const int idx = col - 4096;
      const int kvh = idx >> 7, d = idx & 127, i = (idx & 127) >> 1;
      const float c = cosp[s * 64 + i], sn = sinp[s * 64 + i];
      bf16x2 o = {(bf16)(x1 * c - x2 * sn), (bf16)(x1 * sn + x2 * c)};
      *(bf16x2*)&Ko[((size_t)(b * NKV + kvh) * SEQ + s) * DH + d] = o;
    } else {
      const int idx = col - 5120;
      const int kvh = idx >> 7, d = idx & 127;
      bf16* vbase = VTo + ((size_t)(b * NKV + kvh) * DH + d) * SEQ + s;
      vbase[0] = x.x;
      vbase[SEQ] = x.y;
    }
  }
}

// ======== causal GQA flash attention v2: 8-wave blocks, LDS-staged K/V ========
// Block = (b, h, Tb): paired q panels rows [Tb*128, +128) and [(7-Tb)*128, +128);
// wave w owns 16 rows of each. Grid 256 = 1 block/CU; per-block work = 18 tile-streams.
// K [64][128] + V^T [128][64] tiles staged via global_load_lds into 3 rotating LDS
// buffers (32 KB each), counted VMCNT(4) (2-tile lead), XOR swizzle slot^=(row&7)
// with pre-swizzled global source; frag b128 reads span all 32 banks (structural min).
__global__ __launch_bounds__(512, 2) void flash_attn(const bf16* __restrict__ Q,
                                                     const bf16* __restrict__ K,
                                                     const bf16* __restrict__ VT,
                                                     bf16* __restrict__ O) {
  extern __shared__ char smem[];
  const int t = threadIdx.x, lane = t & 63, w = t >> 6;
  const int l16 = lane & 15, lq = lane >> 4;
  const int p = blockIdx.x;
  const int b = p >> 7, h = (p >> 2) & 31, Tb = p & 3;
  const int kvh = h >> 2;

  const bf16* Qb = Q + (size_t)(b * NH + h) * SEQ * DH;
  const bf16* Kb = K + (size_t)(b * NKV + kvh) * SEQ * DH;
  const bf16* Vb = VT + (size_t)(b * NKV + kvh) * DH * SEQ;

  const int qrA = Tb * 128 + w * 16;
  const int qrB = (7 - Tb) * 128 + w * 16;
  const int nAw = (qrA >> 6) + 1;  // tiles this wave's A stream needs
  const int nBw = (qrB >> 6) + 1;  // > nAw always
  const int NT = 16 - 2 * Tb;      // block loop bound (= max nBw over waves)

  bf16* plw = (bf16*)(smem + 98304) + w * (2 * 16 * 72);  // wave-private P tiles

  // staging sources (pre-swizzled global, linear LDS dest). K tile rows of 256B
  // (16 slots), V tile rows of 128B (8 slots); phys slot p holds global slot p^(row&7).
  const bf16* kSrc = Kb + (size_t)(t >> 4) * DH + 8 * ((t & 15) ^ ((t >> 4) & 7));
  const bf16* vSrc = Vb + (size_t)(t >> 3) * SEQ + 8 * ((t & 7) ^ ((t >> 3) & 7));

  auto stage = [&](int kv) {  // 4 async16/thread: K 16KB + V 16KB
    char* bufb = smem + (kv % 3) * 32768;
    async16(kSrc + (size_t)(kv * 64) * DH, bufb + t * 16);
    async16(kSrc + (size_t)(kv * 64 + 32) * DH, bufb + 8192 + t * 16);
    async16(vSrc + kv * 64, bufb + 16384 + t * 16);
    async16(vSrc + (size_t)64 * SEQ + kv * 64, bufb + 24576 + t * 16);
  };

  // swizzled fragment xor-offsets (row&7 == l16&7 for all frag rows)
  int KX[4], VX[2];
#pragma unroll
  for (int kk = 0; kk < 4; ++kk) KX[kk] = ((kk * 4 + lq) ^ (l16 & 7)) << 4;
#pragma unroll
  for (int c = 0; c < 2; ++c) VX[c] = ((c * 4 + lq) ^ (l16 & 7)) << 4;

  bf16x8 qfA[4], qfB[4];
#pragma unroll
  for (int kk = 0; kk < 4; ++kk) {
    qfA[kk] = *(const bf16x8*)&Qb[(size_t)(qrA + l16) * DH + kk * 32 + lq * 8];
    qfB[kk] = *(const bf16x8*)&Qb[(size_t)(qrB + l16) * DH + kk * 32 + lq * 8];
  }

  f32x4 accA[8] = {}, accB[8] = {};
  float mA[4], lA[4], mB[4], lB[4];
#pragma unroll
  for (int r = 0; r < 4; ++r) {
    mA[r] = mB[r] = -INFINITY;
    lA[r] = lB[r] = 0.f;
  }

  auto finish = [&](f32x4(&s)[4], float(&m)[4], float(&l)[4], f32x4(&acc)[8], int slot,
                    bool mask, int kv, int qr) {
    if (mask) {
#pragma unroll
      for (int nt = 0; nt < 4; ++nt)
#pragma unroll
        for (int r = 0; r < 4; ++r)
          if (kv * 64 + nt * 16 + l16 > qr + lq * 4 + r) s[nt][r] = -INFINITY;
    }
#pragma unroll
    for (int r = 0; r < 4; ++r) {
      float mx = fmaxf(fmaxf(s[0][r], s[1][r]), fmaxf(s[2][r], s[3][r]));
#pragma unroll
      for (int off = 1; off < 16; off <<= 1) mx = fmaxf(mx, __shfl_xor(mx, off));
      const float mn = fmaxf(m[r], mx);
      const float corr = __expf(m[r] - mn);
      m[r] = mn;
      float ps = 0.f;
#pragma unroll
      for (int nt = 0; nt < 4; ++nt) {
        const float pv = __expf(s[nt][r] - mn);
        s[nt][r] = pv;
        ps += pv;
      }
#pragma unroll
      for (int off = 1; off < 16; off <<= 1) ps += __shfl_xor(ps, off);
      l[r] = l[r] * corr + ps;
#pragma unroll
      for (int j = 0; j < 8; ++j) acc[j][r] *= corr;
    }
#pragma unroll
    for (int nt = 0; nt < 4; ++nt)
#pragma unroll
      for (int r = 0; r < 4; ++r)
        plw[slot * 1152 + (lq * 4 + r) * 72 + nt * 16 + l16] = (bf16)s[nt][r];
  };

  stage(0);
  stage(1);
  VMCNT(4);
  barrier_raw();

  for (int kv = 0; kv < NT; ++kv) {
    const char* kbuf = smem + (kv % 3) * 32768;
    const char* vbuf = kbuf + 16384;
    if (kv + 2 < NT) stage(kv + 2);

    if (kv < nAw) {  // dual stream (nAw < nBw always)
      f32x4 sA[4] = {}, sB[4] = {};
      __builtin_amdgcn_s_setprio(1);
#pragma unroll
      for (int nt = 0; nt < 4; ++nt) {
        const char* kr = kbuf + (nt * 16 + l16) * 256;
        bf16x8 k0 = *(const bf16x8*)(kr + KX[0]);
        bf16x8 k1 = *(const bf16x8*)(kr + KX[1]);
        bf16x8 k2 = *(const bf16x8*)(kr + KX[2]);
        bf16x8 k3 = *(const bf16x8*)(kr + KX[3]);
        sA[nt] = MFMA(qfA[0], k0, sA[nt]);
        sB[nt] = MFMA(qfB[0], k0, sB[nt]);
        sA[nt] = MFMA(qfA[1], k1, sA[nt]);
        sB[nt] = MFMA(qfB[1], k1, sB[nt]);
        sA[nt] = MFMA(qfA[2], k2, sA[nt]);
        sB[nt] = MFMA(qfB[2], k2, sB[nt]);
        sA[nt] = MFMA(qfA[3], k3, sA[nt]);
        sB[nt] = MFMA(qfB[3], k3, sB[nt]);
      }
      __builtin_amdgcn_s_setprio(0);
      finish(sA, mA, lA, accA, 0, kv == nAw - 1, kv, qrA);
      finish(sB, mB, lB, accB, 1, kv == nBw - 1, kv, qrB);
      bf16x8 pA0 = *(const bf16x8*)&plw[l16 * 72 + lq * 8];
      bf16x8 pA1 = *(const bf16x8*)&plw[l16 * 72 + 32 + lq * 8];
      bf16x8 pB0 = *(const bf16x8*)&plw[1152 + l16 * 72 + lq * 8];
      bf16x8 pB1 = *(const bf16x8*)&plw[1152 + l16 * 72 + 32 + lq * 8];
      __builtin_amdgcn_s_setprio(1);
#pragma unroll
      for (int j = 0; j < 8; ++j) {
        const char* vr = vbuf + (j * 16 + l16) * 128;
        bf16x8 v0 = *(const bf16x8*)(vr + VX[0]);
        bf16x8 v1 = *(const bf16x8*)(vr + VX[1]);
        accA[j] = MFMA(pA0, v0, accA[j]);
        accB[j] = MFMA(pB0, v0, accB[j]);
        accA[j] = MFMA(pA1, v1, accA[j]);
        accB[j] = MFMA(pB1, v1, accB[j]);
      }
      __builtin_amdgcn_s_setprio(0);
    } else if (kv < nBw) {  // B only
      f32x4 sB[4] = {};
      __builtin_amdgcn_s_setprio(1);
#pragma unroll
      for (int nt = 0; nt < 4; ++nt) {
        const char* kr = kbuf + (nt * 16 + l16) * 256;
        bf16x8 k0 = *(const bf16x8*)(kr + KX[0]);
        bf16x8 k1 = *(const bf16x8*)(kr + KX[1]);
        bf16x8 k2 = *(const bf16x8*)(kr + KX[2]);
        bf16x8 k3 = *(const bf16x8*)(kr + KX[3]);
        sB[nt] = MFMA(qfB[0], k0, sB[nt]);
        sB[nt] = MFMA(qfB[1], k1, sB[nt]);
        sB[nt] = MFMA(qfB[2], k2, sB[nt]);
        sB[nt] = MFMA(qfB[3], k3, sB[nt]);
      }
      __builtin_amdgcn_s_setprio(0);
      finish(sB, mB, lB, accB, 1, kv == nBw - 1, kv, qrB);
      bf16x8 pB0 = *(const bf16x8*)&plw[1152 + l16 * 72 + lq * 8];
      bf16x8 pB1 = *(const bf16x8*)&plw[1152 + l16 * 72 + 32 + lq * 8];
      __builtin_amdgcn_s_setprio(1);
#pragma unroll
      for (int j = 0; j < 8; ++j) {
        const char* vr = vbuf + (j * 16 + l16) * 128;
        bf16x8 v0 = *(const bf16x8*)(vr + VX[0]);
        bf16x8 v1 = *(const bf16x8*)(vr + VX[1]);
        accB[j] = MFMA(pB0, v0, accB[j]);
        accB[j] = MFMA(pB1, v1, accB[j]);
      }
      __builtin_amdgcn_s_setprio(0);
    }

    if (kv + 2 < NT) { VMCNT(4); } else { VMCNT(0); }
    barrier_raw();
  }

  auto wout = [&](f32x4(&acc)[8], float(&l)[4], int qr) {
#pragma unroll
    for (int r = 0; r < 4; ++r) {
      const float inv = 1.f / l[r];
      const size_t orow = ((size_t)b * SEQ + qr + lq * 4 + r) * HIDN + h * DH;
#pragma unroll
      for (int j = 0; j < 8; ++j) O[orow + j * 16 + l16] = (bf16)(acc[j][r] * inv);
    }
  };
  wout(accA, lA, qrA);
  wout(accB, lB, qrB);
}

extern "C" void kernel_launch(void* const* d_in, const int* in_sizes, int n_in,
                              void* d_out, int out_size, void* d_ws, size_t ws_size,
                              hipStream_t stream) {
  const float* hidden = (const float*)d_in[0];
  const float* cosp = (const float*)d_in[1];
  const float* sinp = (const float*)d_in[2];
  const float* wqkv = (const float*)d_in[3];
  const float* wo = (const float*)d_in[4];
  float* out = (float*)d_out;

  char* ws = (char*)d_ws;
  bf16* hiddenB = (bf16*)(ws);                 // 16,777,216   [2048][4096]
  bf16* wqkvT  = (bf16*)(ws + 16777216);       // 50,331,648   [6144][4096]
  bf16* woT    = (bf16*)(ws + 67108864);       // 33,554,432   [4096][4096]
  bf16* qkvB   = (bf16*)(ws + 100663296);      // 25,165,824   [2048][6144]
  bf16* Qb     = (bf16*)(ws + 125829120);      // 16,777,216   [2][32][1024][128]
  bf16* Kb     = (bf16*)(ws + 142606336);      //  4,194,304   [2][8][1024][128]
  bf16* VTb    = (bf16*)(ws + 146800640);      //  4,194,304   [2][8][128][1024]
  bf16* attnB  = hiddenB;                      // alias: hiddenB dead after gemm1

  cvt_f32_bf16<<<8192, 256, 0, stream>>>(hidden, hiddenB, 2097152);
  transpose_cvt<<<dim3(192, 128), 256, 0, stream>>>(wqkv, wqkvT, 4096, 6144);
  transpose_cvt<<<dim3(128, 128), 256, 0, stream>>>(wo, woT, 4096, 4096);
  gemm_dp<384, 1><<<dim3(256), 512, 131072, stream>>>(hiddenB, wqkvT, qkvB, 6144, 4096);
  rope_reshape<<<2048, 256, 0, stream>>>(qkvB, cosp, sinp, Qb, Kb, VTb);
  flash_attn<<<dim3(256), 512, 135168, stream>>>(Qb, Kb, VTb, attnB);
  gemm_dp<256, 0><<<dim3(256), 512, 98304, stream>>>(attnB, woT, out, 4096, 4096);
}